// Round 23
// baseline (224.021 us; speedup 1.0000x reference)
//
#include <hip/hip_runtime.h>

#define BB 2
#define CIN 256
#define HH 64
#define WW 64
#define NPIX 4096
#define CD 128
#define CO2 256
#define KOUT 19
#define EPSV 1e-5f
#define SPAD 4356   // 66*66 padded spatial
#define KW9 2304    // 256*9

typedef __attribute__((ext_vector_type(8))) short bf16x8;
typedef __attribute__((ext_vector_type(4))) float f32x4;

__device__ inline unsigned short f2bf(float f) {
  unsigned u = __float_as_uint(f);
  u += 0x7fffu + ((u >> 16) & 1u);   // RNE
  return (unsigned short)(u >> 16);
}
__device__ inline float bf2f(unsigned short h) {
  return __uint_as_float((unsigned)h << 16);
}
__device__ inline void f2bf_pair(float f, unsigned short& hi, unsigned short& lo) {
  hi = f2bf(f);
  const float fhi = __uint_as_float((unsigned)hi << 16);
  lo = f2bf(f - fhi);
}

// ---------------------------------------------------------------------------
// xT is chunk-major: xP[(b*32 + chunk)*SPAD + s]*8 + e, chunk = kkc*4+g (ci>>3).
__global__ __launch_bounds__(64) void zhalo_kernel(
    unsigned short* __restrict__ xThi, unsigned short* __restrict__ xTlo)
{
  const int p = blockIdx.x;
  const int b = blockIdx.y;
  int s;
  if (p < 66) s = p;
  else if (p < 132) s = 65 * 66 + (p - 66);
  else { const int q = p - 132; s = (1 + (q >> 1)) * 66 + (q & 1) * 65; }
  const size_t o = (((size_t)(b * 32 + (threadIdx.x >> 1))) * SPAD + s) * 8
                 + (threadIdx.x & 1) * 4;
  *reinterpret_cast<uint2*>(&xThi[o]) = make_uint2(0, 0);
  *reinterpret_cast<uint2*>(&xTlo[o]) = make_uint2(0, 0);
}

// Transpose+pad into chunk-major layout.
__global__ __launch_bounds__(256) void xpose_kernel(
    const float* __restrict__ x, unsigned short* __restrict__ xThi,
    unsigned short* __restrict__ xTlo)
{
  const int y = blockIdx.x;
  const int cig = blockIdx.y;
  const int b = blockIdx.z;
  __shared__ float Tl[32][65];
  const int t = threadIdx.x;
  {
    const int cl = t >> 3, pg = t & 7;
    const float* src = x + ((size_t)(b * CIN + cig * 32 + cl)) * NPIX + y * 64 + pg * 8;
    const float4 v0 = *reinterpret_cast<const float4*>(src);
    const float4 v1 = *reinterpret_cast<const float4*>(src + 4);
    Tl[cl][pg * 8 + 0] = v0.x; Tl[cl][pg * 8 + 1] = v0.y;
    Tl[cl][pg * 8 + 2] = v0.z; Tl[cl][pg * 8 + 3] = v0.w;
    Tl[cl][pg * 8 + 4] = v1.x; Tl[cl][pg * 8 + 5] = v1.y;
    Tl[cl][pg * 8 + 6] = v1.z; Tl[cl][pg * 8 + 7] = v1.w;
  }
  __syncthreads();
  {
    const int sl = t >> 2, cg = t & 3;
    unsigned short hh[8], ll[8];
    #pragma unroll
    for (int i = 0; i < 8; ++i) f2bf_pair(Tl[cg * 8 + i][sl], hh[i], ll[i]);
    uint4 ph, pl;
    ph.x = (unsigned)hh[0] | ((unsigned)hh[1] << 16);
    ph.y = (unsigned)hh[2] | ((unsigned)hh[3] << 16);
    ph.z = (unsigned)hh[4] | ((unsigned)hh[5] << 16);
    ph.w = (unsigned)hh[6] | ((unsigned)hh[7] << 16);
    pl.x = (unsigned)ll[0] | ((unsigned)ll[1] << 16);
    pl.y = (unsigned)ll[2] | ((unsigned)ll[3] << 16);
    pl.z = (unsigned)ll[4] | ((unsigned)ll[5] << 16);
    pl.w = (unsigned)ll[6] | ((unsigned)ll[7] << 16);
    const size_t o = (((size_t)(b * 32 + cig * 4 + cg)) * SPAD
                     + (y + 1) * 66 + 1 + sl) * 8;
    *reinterpret_cast<uint4*>(&xThi[o]) = ph;
    *reinterpret_cast<uint4*>(&xTlo[o]) = pl;
  }
}

// Weights packed in MFMA fragment order: wb[cb][q][kkc][g][m][8ci], cb = co>>4.
__global__ __launch_bounds__(256) void wbconv_kernel(
    const float* __restrict__ w_pam, const float* __restrict__ w_cam,
    unsigned short* __restrict__ wbhi, unsigned short* __restrict__ wblo)
{
  const int co = blockIdx.x;
  const float* wsrc = (co < CD) ? (w_pam + (size_t)co * KW9)
                                : (w_cam + (size_t)(co - CD) * KW9);
  const int t = threadIdx.x;
  #pragma unroll
  for (int i = 0; i < 9; ++i) {
    const int idx = i * 256 + t;
    const int q = idx >> 8, ci = idx & 255;
    unsigned short h, l;
    f2bf_pair(wsrc[ci * 9 + q], h, l);
    const size_t dest = ((((size_t)(co >> 4) * 9 + q) * 8 + (ci >> 5)) * 4
                        + ((ci >> 3) & 3)) * 128 + (co & 15) * 8 + (ci & 7);
    wbhi[dest] = h;
    wblo[dest] = l;
  }
}

// Implicit-GEMM conv3x3 via split-bf16 MFMA (round-22 proven, chunk-major x).
__global__ __launch_bounds__(256) void conv_mfma_kernel(
    const unsigned short* __restrict__ xThi, const unsigned short* __restrict__ xTlo,
    const unsigned short* __restrict__ wbhi, const unsigned short* __restrict__ wblo,
    float* __restrict__ out)
{
  const int pxt = blockIdx.x;
  const int cot = blockIdx.y;
  const int b = blockIdx.z;
  const int tid = threadIdx.x;
  const int w = tid >> 6;
  const int lane = tid & 63;
  const int m = lane & 15, g = lane >> 4;
  const int p0 = pxt * 64;
  const int y = p0 >> 6;
  const int sbase = (y + 1) * 66 + 1;

  __shared__ float Obuf[4][64][68];

  f32x4 acc[4][4];
  #pragma unroll
  for (int mt = 0; mt < 4; ++mt)
    #pragma unroll
    for (int jg = 0; jg < 4; ++jg)
      #pragma unroll
      for (int r = 0; r < 4; ++r) acc[mt][jg][r] = 0.f;

  for (int q = 0; q < 9; ++q) {
    const int dq = (q / 3 - 1) * 66 + (q % 3 - 1);
    #pragma unroll
    for (int kk2 = 0; kk2 < 2; ++kk2) {
      const int kkc = w * 2 + kk2;
      const size_t cb = (((size_t)(b * 32 + kkc * 4 + g)) * SPAD + sbase + dq + m) * 8;
      bf16x8 bh[4], bl[4];
      #pragma unroll
      for (int jg = 0; jg < 4; ++jg) {
        bh[jg] = *reinterpret_cast<const bf16x8*>(&xThi[cb + (size_t)(jg * 16) * 8]);
        bl[jg] = *reinterpret_cast<const bf16x8*>(&xTlo[cb + (size_t)(jg * 16) * 8]);
      }
      #pragma unroll
      for (int mt = 0; mt < 4; ++mt) {
        const size_t wbase = ((((size_t)(cot * 4 + mt) * 9 + q) * 8 + kkc) * 4 + g) * 128
                             + m * 8;
        const bf16x8 ah = *reinterpret_cast<const bf16x8*>(&wbhi[wbase]);
        const bf16x8 al = *reinterpret_cast<const bf16x8*>(&wblo[wbase]);
        #pragma unroll
        for (int jg = 0; jg < 4; ++jg) {
          acc[mt][jg] = __builtin_amdgcn_mfma_f32_16x16x32_bf16(ah, bh[jg], acc[mt][jg], 0, 0, 0);
          acc[mt][jg] = __builtin_amdgcn_mfma_f32_16x16x32_bf16(ah, bl[jg], acc[mt][jg], 0, 0, 0);
          acc[mt][jg] = __builtin_amdgcn_mfma_f32_16x16x32_bf16(al, bh[jg], acc[mt][jg], 0, 0, 0);
        }
      }
    }
  }

  #pragma unroll
  for (int mt = 0; mt < 4; ++mt)
    #pragma unroll
    for (int jg = 0; jg < 4; ++jg)
      #pragma unroll
      for (int r = 0; r < 4; ++r)
        Obuf[w][mt * 16 + g * 4 + r][jg * 16 + m] = acc[mt][jg][r];
  __syncthreads();

  const int co_l = tid >> 2;
  const int pxq = (tid & 3) * 16;
  float* op = out + ((size_t)b * CO2 + cot * 64 + co_l) * NPIX + p0 + pxq;
  #pragma unroll
  for (int i = 0; i < 4; ++i) {
    float4 s;
    s.x = Obuf[0][co_l][pxq + i * 4 + 0] + Obuf[1][co_l][pxq + i * 4 + 0]
        + Obuf[2][co_l][pxq + i * 4 + 0] + Obuf[3][co_l][pxq + i * 4 + 0];
    s.y = Obuf[0][co_l][pxq + i * 4 + 1] + Obuf[1][co_l][pxq + i * 4 + 1]
        + Obuf[2][co_l][pxq + i * 4 + 1] + Obuf[3][co_l][pxq + i * 4 + 1];
    s.z = Obuf[0][co_l][pxq + i * 4 + 2] + Obuf[1][co_l][pxq + i * 4 + 2]
        + Obuf[2][co_l][pxq + i * 4 + 2] + Obuf[3][co_l][pxq + i * 4 + 2];
    s.w = Obuf[0][co_l][pxq + i * 4 + 3] + Obuf[1][co_l][pxq + i * 4 + 3]
        + Obuf[2][co_l][pxq + i * 4 + 3] + Obuf[3][co_l][pxq + i * 4 + 3];
    *reinterpret_cast<float4*>(&op[i * 4]) = s;
  }
}

// ---------------------------------------------------------------------------
__global__ __launch_bounds__(256) void gn_stats_kernel(
    const float* __restrict__ conv, float* __restrict__ meanb, float* __restrict__ rstdb)
{
  const int g = blockIdx.x;
  const float* base = conv + (size_t)g * (4 * NPIX);
  float s = 0.f, ss = 0.f;
  const float4* b4 = reinterpret_cast<const float4*>(base);
  for (int i = threadIdx.x; i < 4096; i += 256) {
    float4 v = b4[i];
    s += v.x + v.y + v.z + v.w;
    ss += v.x * v.x + v.y * v.y + v.z * v.z + v.w * v.w;
  }
  #pragma unroll
  for (int off = 32; off > 0; off >>= 1) {
    s += __shfl_down(s, off);
    ss += __shfl_down(ss, off);
  }
  __shared__ float rs[4], rss[4];
  const int lane = threadIdx.x & 63, wv = threadIdx.x >> 6;
  if (lane == 0) { rs[wv] = s; rss[wv] = ss; }
  __syncthreads();
  if (threadIdx.x == 0) {
    const float S = rs[0] + rs[1] + rs[2] + rs[3];
    const float SS = rss[0] + rss[1] + rss[2] + rss[3];
    const float inv = 1.f / 16384.f;
    const float m = S * inv;
    const float var = SS * inv - m * m;
    meanb[g] = m;
    rstdb[g] = rsqrtf(var + EPSV);
  }
}

// Fused GN-apply + ReLU + fragment packs (pam: K/V bf16; cam: hi/lo gram frags).
__global__ __launch_bounds__(256) void gn_pack_kernel(
    float* __restrict__ conv, const float* __restrict__ meanb, const float* __restrict__ rstdb,
    const float* __restrict__ sc_pam, const float* __restrict__ bi_pam,
    const float* __restrict__ sc_cam, const float* __restrict__ bi_cam,
    unsigned short* __restrict__ Kf2, unsigned short* __restrict__ Vf2,
    unsigned short* __restrict__ Cfhi, unsigned short* __restrict__ Cflo)
{
  const int px0 = blockIdx.x * 64;
  const int c0  = blockIdx.y * 32;
  const int b   = blockIdx.z;
  __shared__ float Tl[32][72];
  const int t = threadIdx.x;
  {
    const int cl = t >> 3, pg = t & 7;
    const int c = c0 + cl;
    const int gi = (b * 256 + c) >> 2;
    const int head = c >> 7, cc = c & 127;
    const float mean = meanb[gi], rstd = rstdb[gi];
    const float sc = head ? sc_cam[cc] : sc_pam[cc];
    const float bi = head ? bi_cam[cc] : bi_pam[cc];
    float* src = conv + ((size_t)b * CO2 + c) * NPIX + px0 + pg * 8;
    float4 v0 = *reinterpret_cast<const float4*>(src);
    float4 v1 = *reinterpret_cast<const float4*>(src + 4);
    v0.x = fmaxf((v0.x - mean) * rstd * sc + bi, 0.f);
    v0.y = fmaxf((v0.y - mean) * rstd * sc + bi, 0.f);
    v0.z = fmaxf((v0.z - mean) * rstd * sc + bi, 0.f);
    v0.w = fmaxf((v0.w - mean) * rstd * sc + bi, 0.f);
    v1.x = fmaxf((v1.x - mean) * rstd * sc + bi, 0.f);
    v1.y = fmaxf((v1.y - mean) * rstd * sc + bi, 0.f);
    v1.z = fmaxf((v1.z - mean) * rstd * sc + bi, 0.f);
    v1.w = fmaxf((v1.w - mean) * rstd * sc + bi, 0.f);
    *reinterpret_cast<float4*>(src) = v0;
    *reinterpret_cast<float4*>(src + 4) = v1;
    Tl[cl][pg * 8 + 0] = v0.x; Tl[cl][pg * 8 + 1] = v0.y;
    Tl[cl][pg * 8 + 2] = v0.z; Tl[cl][pg * 8 + 3] = v0.w;
    Tl[cl][pg * 8 + 4] = v1.x; Tl[cl][pg * 8 + 5] = v1.y;
    Tl[cl][pg * 8 + 6] = v1.z; Tl[cl][pg * 8 + 7] = v1.w;
  }
  __syncthreads();
  if (c0 < CD) {
    unsigned short* Kb = Kf2 + (size_t)b * 524288;
    unsigned short* Vb = Vf2 + (size_t)b * 524288;
    {
      const int jblk_l = t >> 6, rem = t & 63;
      const int gk = rem >> 4, mk = rem & 15;
      const int jblk = (px0 >> 4) + jblk_l;
      const int kk = c0 >> 5;
      unsigned short h[8];
      #pragma unroll
      for (int e = 0; e < 8; ++e) h[e] = f2bf(Tl[gk * 8 + e][jblk_l * 16 + mk]);
      uint4 packed;
      packed.x = (unsigned)h[0] | ((unsigned)h[1] << 16);
      packed.y = (unsigned)h[2] | ((unsigned)h[3] << 16);
      packed.z = (unsigned)h[4] | ((unsigned)h[5] << 16);
      packed.w = (unsigned)h[6] | ((unsigned)h[7] << 16);
      *reinterpret_cast<uint4*>(&Kb[(size_t)(jblk * 16 + kk * 4 + gk) * 128 + mk * 8]) = packed;
    }
    {
      const int ct_l = t >> 7, kt = (t >> 6) & 1, gv = (t >> 4) & 3, mv = t & 15;
      const int ct = (c0 >> 4) + ct_l;
      const int jc = px0 >> 6;
      unsigned short h[8];
      #pragma unroll
      for (int e = 0; e < 8; ++e) h[e] = f2bf(Tl[ct_l * 16 + mv][kt * 32 + gv * 8 + e]);
      uint4 packed;
      packed.x = (unsigned)h[0] | ((unsigned)h[1] << 16);
      packed.y = (unsigned)h[2] | ((unsigned)h[3] << 16);
      packed.z = (unsigned)h[4] | ((unsigned)h[5] << 16);
      packed.w = (unsigned)h[6] | ((unsigned)h[7] << 16);
      *reinterpret_cast<uint4*>(
          &Vb[(size_t)(((ct * 64 + jc) * 2 + kt) * 4 + gv) * 128 + mv * 8]) = packed;
    }
  } else {
    const int ct_l = t >> 7, kk_l = (t >> 6) & 1, gc = (t >> 4) & 3, mc = t & 15;
    const int ctg = ((c0 - CD) >> 4) + ct_l;
    const int kkg = (px0 >> 5) + kk_l;
    unsigned short hh[8], ll[8];
    #pragma unroll
    for (int e = 0; e < 8; ++e)
      f2bf_pair(Tl[ct_l * 16 + mc][kk_l * 32 + gc * 8 + e], hh[e], ll[e]);
    uint4 ph, pl;
    ph.x = (unsigned)hh[0] | ((unsigned)hh[1] << 16);
    ph.y = (unsigned)hh[2] | ((unsigned)hh[3] << 16);
    ph.z = (unsigned)hh[4] | ((unsigned)hh[5] << 16);
    ph.w = (unsigned)hh[6] | ((unsigned)hh[7] << 16);
    pl.x = (unsigned)ll[0] | ((unsigned)ll[1] << 16);
    pl.y = (unsigned)ll[2] | ((unsigned)ll[3] << 16);
    pl.z = (unsigned)ll[4] | ((unsigned)ll[5] << 16);
    pl.w = (unsigned)ll[6] | ((unsigned)ll[7] << 16);
    const size_t o = (((size_t)(b * 128 + kkg) * 8 + ctg) * 4 + gc) * 128 + mc * 8;
    *reinterpret_cast<uint4*>(&Cfhi[o]) = ph;
    *reinterpret_cast<uint4*>(&Cflo[o]) = pl;
  }
}

// ---------------------------------------------------------------------------
// CAM gram via split-bf16 MFMA, K split across blocks (round-21 proven).
__global__ __launch_bounds__(512) void cam_gram_mfma_kernel(
    const unsigned short* __restrict__ Cfhi, const unsigned short* __restrict__ Cflo,
    float* __restrict__ gpart8)
{
  const int dt = blockIdx.x;
  const int b = blockIdx.y;
  const int kg = blockIdx.z;
  const int tid = threadIdx.x;
  const int w = tid >> 6;
  const int lane = tid & 63;
  const int m = lane & 15, g = lane >> 4;

  __shared__ float Gbuf[4][128][17];

  f32x4 acc[8];
  #pragma unroll
  for (int ct = 0; ct < 8; ++ct)
    #pragma unroll
    for (int r = 0; r < 4; ++r) acc[ct][r] = 0.f;

  const int kk = kg * 8 + w;
  const size_t base = (size_t)(b * 128 + kk) * 8;
  const bf16x8 dh = *reinterpret_cast<const bf16x8*>(&Cfhi[((base + dt) * 4 + g) * 128 + m * 8]);
  const bf16x8 dl = *reinterpret_cast<const bf16x8*>(&Cflo[((base + dt) * 4 + g) * 128 + m * 8]);
  #pragma unroll
  for (int ct = 0; ct < 8; ++ct) {
    const bf16x8 ah = *reinterpret_cast<const bf16x8*>(&Cfhi[((base + ct) * 4 + g) * 128 + m * 8]);
    const bf16x8 al = *reinterpret_cast<const bf16x8*>(&Cflo[((base + ct) * 4 + g) * 128 + m * 8]);
    acc[ct] = __builtin_amdgcn_mfma_f32_16x16x32_bf16(ah, dh, acc[ct], 0, 0, 0);
    acc[ct] = __builtin_amdgcn_mfma_f32_16x16x32_bf16(ah, dl, acc[ct], 0, 0, 0);
    acc[ct] = __builtin_amdgcn_mfma_f32_16x16x32_bf16(al, dh, acc[ct], 0, 0, 0);
  }

  if (w < 4) {
    #pragma unroll
    for (int ct = 0; ct < 8; ++ct)
      #pragma unroll
      for (int r = 0; r < 4; ++r)
        Gbuf[w][ct * 16 + g * 4 + r][m] = acc[ct][r];
  }
  __syncthreads();
  if (w >= 4) {
    #pragma unroll
    for (int ct = 0; ct < 8; ++ct)
      #pragma unroll
      for (int r = 0; r < 4; ++r)
        Gbuf[w - 4][ct * 16 + g * 4 + r][m] += acc[ct][r];
  }
  __syncthreads();
  const int c = tid >> 2;
  const int d0 = (tid & 3) * 4;
  float* gp = gpart8 + (((size_t)(kg * BB + b) * 128 + c)) * 128 + dt * 16;
  #pragma unroll
  for (int j = 0; j < 4; ++j) {
    const int d = d0 + j;
    gp[d] = Gbuf[0][c][d] + Gbuf[1][c][d] + Gbuf[2][c][d] + Gbuf[3][c][d];
  }
}

// Reduce 16 kg partials + row softmax -> camw[b][c][d].
__global__ __launch_bounds__(128) void cam_softmax_kernel(
    const float* __restrict__ gpart8, float* __restrict__ camw)
{
  const int bc = blockIdx.x;
  const int b = bc >> 7, c = bc & 127;
  const int d = threadIdx.x;
  float g = 0.f;
  #pragma unroll
  for (int s = 0; s < 16; ++s)
    g += gpart8[(((size_t)(s * BB + b) * 128 + c)) * 128 + d];
  float m = g;
  #pragma unroll
  for (int off = 32; off > 0; off >>= 1) m = fmaxf(m, __shfl_xor(m, off));
  __shared__ float sm[2], ssum[2];
  const int lane = d & 63, wv = d >> 6;
  if (lane == 0) sm[wv] = m;
  __syncthreads();
  m = fmaxf(sm[0], sm[1]);
  const float e = __expf(g - m);
  float s = e;
  #pragma unroll
  for (int off = 32; off > 0; off >>= 1) s += __shfl_xor(s, off);
  if (lane == 0) ssum[wv] = s;
  __syncthreads();
  camw[(size_t)bc * CD + d] = e / (ssum[0] + ssum[1]);
}

// sum_cam = cam + camw @ Am. c-tile 16 (Am re-read 4x less). grid (4, 8, 2).
__global__ __launch_bounds__(256) void cam_apply_kernel(
    const float* __restrict__ conv, const float* __restrict__ camw, float* __restrict__ scam)
{
  const int b = blockIdx.z;
  const int c0 = blockIdx.y * 16;
  const int n = blockIdx.x * 1024 + threadIdx.x;
  const float* Am = conv + ((size_t)b * CO2 + CD) * NPIX;
  const float* Wr = camw + ((size_t)b * CD + c0) * CD;
  float acc[16][4];
  #pragma unroll
  for (int i = 0; i < 16; ++i)
    #pragma unroll
    for (int k = 0; k < 4; ++k) acc[i][k] = 0.f;
  for (int d = 0; d < CD; ++d) {
    float wv[16];
    #pragma unroll
    for (int i = 0; i < 16; ++i) wv[i] = Wr[(size_t)i * CD + d];
    #pragma unroll
    for (int k = 0; k < 4; ++k) {
      const float a = Am[(size_t)d * NPIX + n + k * 256];
      #pragma unroll
      for (int i = 0; i < 16; ++i) acc[i][k] += wv[i] * a;
    }
  }
  #pragma unroll
  for (int i = 0; i < 16; ++i)
    #pragma unroll
    for (int k = 0; k < 4; ++k)
      scam[((size_t)b * CD + c0 + i) * NPIX + n + k * 256] =
          Am[(size_t)(c0 + i) * NPIX + n + k * 256] + acc[i][k];
}

// ---------------------------------------------------------------------------
// PAM flash attention via bf16 MFMA, fragment-packed K/V, batched fragment
// loads (hide L2 latency: 8 loads issue before the MFMAs that consume them).
__global__ __launch_bounds__(512) void pam_mfma_kernel(
    const unsigned short* __restrict__ Kf2, const unsigned short* __restrict__ Vf2,
    unsigned short* __restrict__ Opart, float* __restrict__ mpart,
    float* __restrict__ lpart)
{
  const int tile = blockIdx.x;
  const int b = blockIdx.y;
  const int kg = blockIdx.z;
  const int q0 = tile * 32;
  const int tid = threadIdx.x;
  const int w = tid >> 6;
  const int lane = tid & 63;
  const int m = lane & 15, g = lane >> 4;

  __shared__ __align__(16) unsigned short Sl[8][32 * 72];
  __shared__ unsigned short Obuf[4][32][130];
  __shared__ float mlm[8][32], mll[8][32], mst[32], ltt[32];

  const unsigned short* Kb = Kf2 + (size_t)b * 524288;
  const unsigned short* Vb = Vf2 + (size_t)b * 524288;

  bf16x8 qf[2][4];
  #pragma unroll
  for (int s = 0; s < 2; ++s)
    #pragma unroll
    for (int kk = 0; kk < 4; ++kk)
      qf[s][kk] = *reinterpret_cast<const bf16x8*>(
          &Kb[(size_t)(((q0 >> 4) + s) * 16 + kk * 4 + g) * 128 + m * 8]);

  f32x4 oacc[2][8];
  #pragma unroll
  for (int s = 0; s < 2; ++s)
    #pragma unroll
    for (int ct = 0; ct < 8; ++ct)
      #pragma unroll
      for (int r = 0; r < 4; ++r) oacc[s][ct][r] = 0.f;

  float mrow[2][4], lrow[2][4];
  #pragma unroll
  for (int s = 0; s < 2; ++s)
    #pragma unroll
    for (int r = 0; r < 4; ++r) { mrow[s][r] = -1e30f; lrow[s][r] = 0.f; }

  for (int t = kg * 32 + w * 4; t < kg * 32 + w * 4 + 4; ++t) {
    f32x4 sacc[2][4];
    #pragma unroll
    for (int s = 0; s < 2; ++s)
      #pragma unroll
      for (int jt = 0; jt < 4; ++jt)
        #pragma unroll
        for (int r = 0; r < 4; ++r) sacc[s][jt][r] = 0.f;
    // QK^T: batch loads per jt-pair so 8 loads are in flight before use
    #pragma unroll
    for (int jp = 0; jp < 2; ++jp) {
      bf16x8 kf[2][4];
      #pragma unroll
      for (int j2 = 0; j2 < 2; ++j2)
        #pragma unroll
        for (int kk = 0; kk < 4; ++kk)
          kf[j2][kk] = *reinterpret_cast<const bf16x8*>(
              &Kb[(size_t)((t * 4 + jp * 2 + j2) * 16 + kk * 4 + g) * 128 + m * 8]);
      #pragma unroll
      for (int j2 = 0; j2 < 2; ++j2) {
        const int jt = jp * 2 + j2;
        #pragma unroll
        for (int kk = 0; kk < 4; ++kk) {
          sacc[0][jt] = __builtin_amdgcn_mfma_f32_16x16x32_bf16(qf[0][kk], kf[j2][kk], sacc[0][jt], 0, 0, 0);
          sacc[1][jt] = __builtin_amdgcn_mfma_f32_16x16x32_bf16(qf[1][kk], kf[j2][kk], sacc[1][jt], 0, 0, 0);
        }
      }
    }
    float facq[2];
    #pragma unroll
    for (int s = 0; s < 2; ++s) {
      float fac[4];
      #pragma unroll
      for (int r = 0; r < 4; ++r) {
        float v = fmaxf(fmaxf(sacc[s][0][r], sacc[s][1][r]), fmaxf(sacc[s][2][r], sacc[s][3][r]));
        v = fmaxf(v, __shfl_xor(v, 1));
        v = fmaxf(v, __shfl_xor(v, 2));
        v = fmaxf(v, __shfl_xor(v, 4));
        v = fmaxf(v, __shfl_xor(v, 8));
        const float mn = fmaxf(mrow[s][r], v);
        fac[r] = __expf(fmaxf(mrow[s][r] - mn, -80.f));
        mrow[s][r] = mn;
      }
      #pragma unroll
      for (int r = 0; r < 4; ++r) {
        float ls = 0.f;
        #pragma unroll
        for (int jt = 0; jt < 4; ++jt) {
          const float e = __expf(sacc[s][jt][r] - mrow[s][r]);
          ls += e;
          Sl[w][(s * 16 + g * 4 + r) * 72 + jt * 16 + m] = f2bf(e);
        }
        ls += __shfl_xor(ls, 1);
        ls += __shfl_xor(ls, 2);
        ls += __shfl_xor(ls, 4);
        ls += __shfl_xor(ls, 8);
        lrow[s][r] = lrow[s][r] * fac[r] + ls;
      }
      const int sel = m & 3;
      const float fsel = (sel == 0) ? fac[0] : (sel == 1) ? fac[1] : (sel == 2) ? fac[2] : fac[3];
      facq[s] = __shfl(fsel, ((m >> 2) << 4) | sel);
    }
    #pragma unroll
    for (int s = 0; s < 2; ++s)
      #pragma unroll
      for (int ct = 0; ct < 8; ++ct)
        #pragma unroll
        for (int r = 0; r < 4; ++r) oacc[s][ct][r] *= facq[s];
    bf16x8 pf[2][2];
    #pragma unroll
    for (int s = 0; s < 2; ++s)
      #pragma unroll
      for (int kt = 0; kt < 2; ++kt)
        pf[s][kt] = *reinterpret_cast<const bf16x8*>(&Sl[w][(s * 16 + m) * 72 + kt * 32 + g * 8]);
    // PV: batch loads per ct-quad (8 loads in flight)
    #pragma unroll
    for (int cp = 0; cp < 2; ++cp) {
      bf16x8 vf[4][2];
      #pragma unroll
      for (int c2 = 0; c2 < 4; ++c2)
        #pragma unroll
        for (int kt = 0; kt < 2; ++kt)
          vf[c2][kt] = *reinterpret_cast<const bf16x8*>(
              &Vb[(size_t)((((cp * 4 + c2) * 64 + t) * 2 + kt) * 4 + g) * 128 + m * 8]);
      #pragma unroll
      for (int c2 = 0; c2 < 4; ++c2) {
        const int ct = cp * 4 + c2;
        #pragma unroll
        for (int kt = 0; kt < 2; ++kt) {
          oacc[0][ct] = __builtin_amdgcn_mfma_f32_16x16x32_bf16(vf[c2][kt], pf[0][kt], oacc[0][ct], 0, 0, 0);
          oacc[1][ct] = __builtin_amdgcn_mfma_f32_16x16x32_bf16(vf[c2][kt], pf[1][kt], oacc[1][ct], 0, 0, 0);
        }
      }
    }
  }

  float mq[2], lq[2];
  #pragma unroll
  for (int s = 0; s < 2; ++s) {
    const int sel = m & 3;
    const float msel_ = (sel == 0) ? mrow[s][0] : (sel == 1) ? mrow[s][1]
                       : (sel == 2) ? mrow[s][2] : mrow[s][3];
    mq[s] = __shfl(msel_, ((m >> 2) << 4) | sel);
    const float lsel_ = (sel == 0) ? lrow[s][0] : (sel == 1) ? lrow[s][1]
                       : (sel == 2) ? lrow[s][2] : lrow[s][3];
    lq[s] = __shfl(lsel_, ((m >> 2) << 4) | sel);
  }
  if (g == 0) {
    #pragma unroll
    for (int s = 0; s < 2; ++s) { mlm[w][s * 16 + m] = mq[s]; mll[w][s * 16 + m] = lq[s]; }
  }
  __syncthreads();
  float rsw[2];
  #pragma unroll
  for (int s = 0; s < 2; ++s) {
    const int row = s * 16 + m;
    float ms = mlm[0][row];
    #pragma unroll
    for (int sw = 1; sw < 8; ++sw) ms = fmaxf(ms, mlm[sw][row]);
    rsw[s] = __expf(fmaxf(mq[s] - ms, -80.f));
  }
  if (w < 4) {
    #pragma unroll
    for (int s = 0; s < 2; ++s)
      #pragma unroll
      for (int ct = 0; ct < 8; ++ct)
        #pragma unroll
        for (int r = 0; r < 4; ++r)
          Obuf[w][s * 16 + m][ct * 16 + g * 4 + r] = f2bf(oacc[s][ct][r] * rsw[s]);
  }
  if (w == 0 && g == 0) {
    #pragma unroll
    for (int s = 0; s < 2; ++s) {
      const int row = s * 16 + m;
      float ms = mlm[0][row];
      #pragma unroll
      for (int sw = 1; sw < 8; ++sw) ms = fmaxf(ms, mlm[sw][row]);
      float lt = 0.f;
      #pragma unroll
      for (int sw = 0; sw < 8; ++sw)
        lt += mll[sw][row] * __expf(fmaxf(mlm[sw][row] - ms, -80.f));
      mst[row] = ms;
      ltt[row] = lt;
    }
  }
  __syncthreads();
  if (w >= 4) {
    #pragma unroll
    for (int s = 0; s < 2; ++s)
      #pragma unroll
      for (int ct = 0; ct < 8; ++ct)
        #pragma unroll
        for (int r = 0; r < 4; ++r) {
          unsigned short* pp = &Obuf[w - 4][s * 16 + m][ct * 16 + g * 4 + r];
          *pp = f2bf(bf2f(*pp) + oacc[s][ct][r] * rsw[s]);
        }
  }
  __syncthreads();
  const size_t pbase = ((size_t)(kg * BB + b) * 128 + tile) * 32;
  unsigned short* Op = Opart + pbase * 128;
  const int c = tid >> 2;
  const int qh = (tid & 3) * 8;
  #pragma unroll
  for (int qq = 0; qq < 8; ++qq) {
    const int row = qh + qq;
    float o = 0.f;
    #pragma unroll
    for (int sw = 0; sw < 4; ++sw) o += bf2f(Obuf[sw][row][c]);
    Op[(size_t)row * 128 + c] = f2bf(o);
  }
  if (tid < 32) {
    mpart[pbase + tid] = mst[tid];
    lpart[pbase + tid] = ltt[tid];
  }
}

// Combine the two kg partials exactly; add conv residual.
__global__ __launch_bounds__(256) void pam_merge_kernel(
    const float* __restrict__ conv, const unsigned short* __restrict__ Opart,
    const float* __restrict__ mpart, const float* __restrict__ lpart,
    float* __restrict__ spam)
{
  const int tile = blockIdx.x;
  const int b = blockIdx.y;
  const int tid = threadIdx.x;
  const int c = tid & 127;
  const int rg = tid >> 7;
  const size_t i0 = ((size_t)(0 * BB + b) * 128 + tile) * 32;
  const size_t i1 = ((size_t)(1 * BB + b) * 128 + tile) * 32;
  #pragma unroll
  for (int rr = 0; rr < 16; ++rr) {
    const int row = rg * 16 + rr;
    const float m0 = mpart[i0 + row], m1 = mpart[i1 + row];
    const float ms = fmaxf(m0, m1);
    const float w0 = __expf(fmaxf(m0 - ms, -80.f));
    const float w1 = __expf(fmaxf(m1 - ms, -80.f));
    const float l = lpart[i0 + row] * w0 + lpart[i1 + row] * w1;
    const float o = bf2f(Opart[(i0 + row) * 128 + c]) * w0
                  + bf2f(Opart[(i1 + row) * 128 + c]) * w1;
    const int q = tile * 32 + row;
    spam[((size_t)b * CD + c) * NPIX + q] =
        conv[((size_t)b * CO2 + c) * NPIX + q] + o / l;
  }
}

// ---------------------------------------------------------------------------
__global__ __launch_bounds__(256) void pred_part_kernel(
    const float* __restrict__ spam, const float* __restrict__ scam,
    const float* __restrict__ wpred, float* __restrict__ psum)
{
  const int p = blockIdx.x * 256 + threadIdx.x;
  const int slice = blockIdx.y;
  const int b = blockIdx.z;
  float acc[KOUT];
  #pragma unroll
  for (int k = 0; k < KOUT; ++k) acc[k] = 0.f;
  const float* sp = spam + (size_t)b * CD * NPIX + p;
  const float* sc = scam + (size_t)b * CD * NPIX + p;
  #pragma unroll
  for (int ci = 0; ci < 16; ++ci) {
    const int c = slice * 16 + ci;
    const float f = sp[(size_t)c * NPIX] + sc[(size_t)c * NPIX];
    #pragma unroll
    for (int k = 0; k < KOUT; ++k)
      acc[k] += f * wpred[k * CD + c];
  }
  #pragma unroll
  for (int k = 0; k < KOUT; ++k)
    psum[(((size_t)slice * BB + b) * KOUT + k) * NPIX + p] = acc[k];
}

__global__ __launch_bounds__(256) void pred_reduce_kernel(
    const float* __restrict__ psum, const float* __restrict__ bpred,
    float* __restrict__ logit)
{
  const int p = blockIdx.x * 256 + threadIdx.x;
  const int b = blockIdx.y;
  #pragma unroll
  for (int k = 0; k < KOUT; ++k) {
    float s = bpred[k];
    #pragma unroll
    for (int sl = 0; sl < 8; ++sl)
      s += psum[(((size_t)sl * BB + b) * KOUT + k) * NPIX + p];
    logit[((size_t)b * KOUT + k) * NPIX + p] = s;
  }
}

__global__ __launch_bounds__(256) void upsample_kernel(
    const float* __restrict__ logit, float* __restrict__ out)
{
  const int idx = blockIdx.x * 256 + threadIdx.x;
  if (idx >= BB * KOUT * 256 * 256) return;
  const int ox = idx & 255;
  const int oy = (idx >> 8) & 255;
  const int plane = idx >> 16;
  const float* src = logit + (size_t)plane * NPIX;
  const float sy = (oy + 0.5f) * 0.25f - 0.5f;
  const float sx = (ox + 0.5f) * 0.25f - 0.5f;
  const float fyf = floorf(sy), fxf = floorf(sx);
  const float wy = sy - fyf, wx = sx - fxf;
  const int y0 = (int)fyf, x0 = (int)fxf;
  const int y0c = y0 < 0 ? 0 : y0;
  const int y1c = (y0 + 1 > 63) ? 63 : y0 + 1;
  const int x0c = x0 < 0 ? 0 : x0;
  const int x1c = (x0 + 1 > 63) ? 63 : x0 + 1;
  const float v00 = src[y0c * 64 + x0c], v01 = src[y0c * 64 + x1c];
  const float v10 = src[y1c * 64 + x0c], v11 = src[y1c * 64 + x1c];
  const float top = v00 + (v01 - v00) * wx;
  const float bot = v10 + (v11 - v10) * wx;
  out[idx] = top + (bot - top) * wy;
}

// ---------------------------------------------------------------------------
extern "C" void kernel_launch(void* const* d_in, const int* in_sizes, int n_in,
                              void* d_out, int out_size, void* d_ws, size_t ws_size,
                              hipStream_t stream) {
  (void)in_sizes; (void)n_in; (void)out_size; (void)ws_size;
  const float* x      = (const float*)d_in[0];
  const float* w_pam  = (const float*)d_in[1];
  const float* s_pam  = (const float*)d_in[2];
  const float* b_pam  = (const float*)d_in[3];
  const float* w_cam  = (const float*)d_in[4];
  const float* s_cam  = (const float*)d_in[5];
  const float* b_cam  = (const float*)d_in[6];
  const float* w_pred = (const float*)d_in[7];
  const float* b_pred = (const float*)d_in[8];
  float* out_f = (float*)d_out;
  float* ws0 = (float*)d_ws;

  // workspace layout (floats), total 5,138,688 = 20.55 MB (unchanged)
  float* conv  = ws0;
  unsigned short* xThi = (unsigned short*)(ws0 + 2097152);
  unsigned short* xTlo = xThi + (size_t)BB * 32 * SPAD * 8;
  unsigned short* wbhi = (unsigned short*)(ws0 + 4327424);
  unsigned short* wblo = wbhi + (size_t)CO2 * KW9;
  unsigned short* Cfhi = (unsigned short*)(ws0 + 3145728);
  unsigned short* Cflo = (unsigned short*)(ws0 + 3670016);
  unsigned short* Opart = (unsigned short*)(ws0 + 3145728);
  float* psum  = ws0 + 3145728;
  float* mpart = ws0 + 4194304;
  float* lpart = ws0 + 4227072;
  float* gpart8 = ws0 + 4292608;
  float* camw  = ws0 + 4950016;
  float* meanb = ws0 + 4982784;
  float* rstdb = ws0 + 4982912;
  float* logit = ws0 + 4983040;

  unsigned short* Kf2 = xThi;
  unsigned short* Vf2 = Kf2 + 1048576;

  float* spam = out_f;
  float* scam = out_f + 1048576;

  zhalo_kernel<<<dim3(260, 2), 64, 0, stream>>>(xThi, xTlo);
  xpose_kernel<<<dim3(64, 8, 2), 256, 0, stream>>>(x, xThi, xTlo);
  wbconv_kernel<<<256, 256, 0, stream>>>(w_pam, w_cam, wbhi, wblo);
  conv_mfma_kernel<<<dim3(64, 4, 2), 256, 0, stream>>>(xThi, xTlo, wbhi, wblo, conv);
  gn_stats_kernel<<<128, 256, 0, stream>>>(conv, meanb, rstdb);
  gn_pack_kernel<<<dim3(64, 8, 2), 256, 0, stream>>>(conv, meanb, rstdb,
      s_pam, b_pam, s_cam, b_cam, Kf2, Vf2, Cfhi, Cflo);
  cam_gram_mfma_kernel<<<dim3(8, 2, 16), 512, 0, stream>>>(Cfhi, Cflo, gpart8);
  cam_softmax_kernel<<<256, 128, 0, stream>>>(gpart8, camw);
  cam_apply_kernel<<<dim3(4, 8, 2), 256, 0, stream>>>(conv, camw, scam);
  pam_mfma_kernel<<<dim3(128, 2, 2), 512, 0, stream>>>(Kf2, Vf2, Opart, mpart, lpart);
  pam_merge_kernel<<<dim3(128, 2), 256, 0, stream>>>(conv, Opart, mpart, lpart, spam);
  pred_part_kernel<<<dim3(16, 8, 2), 256, 0, stream>>>(spam, scam, w_pred, psum);
  pred_reduce_kernel<<<dim3(16, 2), 256, 0, stream>>>(psum, b_pred, logit);
  upsample_kernel<<<9728, 256, 0, stream>>>(logit, out_f);
}

// Round 24
// 204.063 us; speedup vs baseline: 1.0978x; 1.0978x over previous
//
#include <hip/hip_runtime.h>

#define BB 2
#define CIN 256
#define HH 64
#define WW 64
#define NPIX 4096
#define CD 128
#define CO2 256
#define KOUT 19
#define EPSV 1e-5f
#define SPAD 4356   // 66*66 padded spatial
#define KW9 2304    // 256*9

typedef __attribute__((ext_vector_type(8))) short bf16x8;
typedef __attribute__((ext_vector_type(4))) float f32x4;

__device__ inline unsigned short f2bf(float f) {
  unsigned u = __float_as_uint(f);
  u += 0x7fffu + ((u >> 16) & 1u);   // RNE
  return (unsigned short)(u >> 16);
}
__device__ inline float bf2f(unsigned short h) {
  return __uint_as_float((unsigned)h << 16);
}
__device__ inline void f2bf_pair(float f, unsigned short& hi, unsigned short& lo) {
  hi = f2bf(f);
  const float fhi = __uint_as_float((unsigned)hi << 16);
  lo = f2bf(f - fhi);
}

// ---------------------------------------------------------------------------
// xT is chunk-major: xP[(b*32 + chunk)*SPAD + s]*8 + e, chunk = kkc*4+g (ci>>3).
__global__ __launch_bounds__(64) void zhalo_kernel(
    unsigned short* __restrict__ xThi, unsigned short* __restrict__ xTlo)
{
  const int p = blockIdx.x;
  const int b = blockIdx.y;
  int s;
  if (p < 66) s = p;
  else if (p < 132) s = 65 * 66 + (p - 66);
  else { const int q = p - 132; s = (1 + (q >> 1)) * 66 + (q & 1) * 65; }
  const size_t o = (((size_t)(b * 32 + (threadIdx.x >> 1))) * SPAD + s) * 8
                 + (threadIdx.x & 1) * 4;
  *reinterpret_cast<uint2*>(&xThi[o]) = make_uint2(0, 0);
  *reinterpret_cast<uint2*>(&xTlo[o]) = make_uint2(0, 0);
}

// Transpose+pad into chunk-major layout.
__global__ __launch_bounds__(256) void xpose_kernel(
    const float* __restrict__ x, unsigned short* __restrict__ xThi,
    unsigned short* __restrict__ xTlo)
{
  const int y = blockIdx.x;
  const int cig = blockIdx.y;
  const int b = blockIdx.z;
  __shared__ float Tl[32][65];
  const int t = threadIdx.x;
  {
    const int cl = t >> 3, pg = t & 7;
    const float* src = x + ((size_t)(b * CIN + cig * 32 + cl)) * NPIX + y * 64 + pg * 8;
    const float4 v0 = *reinterpret_cast<const float4*>(src);
    const float4 v1 = *reinterpret_cast<const float4*>(src + 4);
    Tl[cl][pg * 8 + 0] = v0.x; Tl[cl][pg * 8 + 1] = v0.y;
    Tl[cl][pg * 8 + 2] = v0.z; Tl[cl][pg * 8 + 3] = v0.w;
    Tl[cl][pg * 8 + 4] = v1.x; Tl[cl][pg * 8 + 5] = v1.y;
    Tl[cl][pg * 8 + 6] = v1.z; Tl[cl][pg * 8 + 7] = v1.w;
  }
  __syncthreads();
  {
    const int sl = t >> 2, cg = t & 3;
    unsigned short hh[8], ll[8];
    #pragma unroll
    for (int i = 0; i < 8; ++i) f2bf_pair(Tl[cg * 8 + i][sl], hh[i], ll[i]);
    uint4 ph, pl;
    ph.x = (unsigned)hh[0] | ((unsigned)hh[1] << 16);
    ph.y = (unsigned)hh[2] | ((unsigned)hh[3] << 16);
    ph.z = (unsigned)hh[4] | ((unsigned)hh[5] << 16);
    ph.w = (unsigned)hh[6] | ((unsigned)hh[7] << 16);
    pl.x = (unsigned)ll[0] | ((unsigned)ll[1] << 16);
    pl.y = (unsigned)ll[2] | ((unsigned)ll[3] << 16);
    pl.z = (unsigned)ll[4] | ((unsigned)ll[5] << 16);
    pl.w = (unsigned)ll[6] | ((unsigned)ll[7] << 16);
    const size_t o = (((size_t)(b * 32 + cig * 4 + cg)) * SPAD
                     + (y + 1) * 66 + 1 + sl) * 8;
    *reinterpret_cast<uint4*>(&xThi[o]) = ph;
    *reinterpret_cast<uint4*>(&xTlo[o]) = pl;
  }
}

// Weights packed in MFMA fragment order: wb[cb][q][kkc][g][m][8ci], cb = co>>4.
__global__ __launch_bounds__(256) void wbconv_kernel(
    const float* __restrict__ w_pam, const float* __restrict__ w_cam,
    unsigned short* __restrict__ wbhi, unsigned short* __restrict__ wblo)
{
  const int co = blockIdx.x;
  const float* wsrc = (co < CD) ? (w_pam + (size_t)co * KW9)
                                : (w_cam + (size_t)(co - CD) * KW9);
  const int t = threadIdx.x;
  #pragma unroll
  for (int i = 0; i < 9; ++i) {
    const int idx = i * 256 + t;
    const int q = idx >> 8, ci = idx & 255;
    unsigned short h, l;
    f2bf_pair(wsrc[ci * 9 + q], h, l);
    const size_t dest = ((((size_t)(co >> 4) * 9 + q) * 8 + (ci >> 5)) * 4
                        + ((ci >> 3) & 3)) * 128 + (co & 15) * 8 + (ci & 7);
    wbhi[dest] = h;
    wblo[dest] = l;
  }
}

// Implicit-GEMM conv3x3 via split-bf16 MFMA (chunk-major x, round-22 proven).
__global__ __launch_bounds__(256) void conv_mfma_kernel(
    const unsigned short* __restrict__ xThi, const unsigned short* __restrict__ xTlo,
    const unsigned short* __restrict__ wbhi, const unsigned short* __restrict__ wblo,
    float* __restrict__ out)
{
  const int pxt = blockIdx.x;
  const int cot = blockIdx.y;
  const int b = blockIdx.z;
  const int tid = threadIdx.x;
  const int w = tid >> 6;
  const int lane = tid & 63;
  const int m = lane & 15, g = lane >> 4;
  const int p0 = pxt * 64;
  const int y = p0 >> 6;
  const int sbase = (y + 1) * 66 + 1;

  __shared__ float Obuf[4][64][68];

  f32x4 acc[4][4];
  #pragma unroll
  for (int mt = 0; mt < 4; ++mt)
    #pragma unroll
    for (int jg = 0; jg < 4; ++jg)
      #pragma unroll
      for (int r = 0; r < 4; ++r) acc[mt][jg][r] = 0.f;

  for (int q = 0; q < 9; ++q) {
    const int dq = (q / 3 - 1) * 66 + (q % 3 - 1);
    #pragma unroll
    for (int kk2 = 0; kk2 < 2; ++kk2) {
      const int kkc = w * 2 + kk2;
      const size_t cb = (((size_t)(b * 32 + kkc * 4 + g)) * SPAD + sbase + dq + m) * 8;
      bf16x8 bh[4], bl[4];
      #pragma unroll
      for (int jg = 0; jg < 4; ++jg) {
        bh[jg] = *reinterpret_cast<const bf16x8*>(&xThi[cb + (size_t)(jg * 16) * 8]);
        bl[jg] = *reinterpret_cast<const bf16x8*>(&xTlo[cb + (size_t)(jg * 16) * 8]);
      }
      #pragma unroll
      for (int mt = 0; mt < 4; ++mt) {
        const size_t wbase = ((((size_t)(cot * 4 + mt) * 9 + q) * 8 + kkc) * 4 + g) * 128
                             + m * 8;
        const bf16x8 ah = *reinterpret_cast<const bf16x8*>(&wbhi[wbase]);
        const bf16x8 al = *reinterpret_cast<const bf16x8*>(&wblo[wbase]);
        #pragma unroll
        for (int jg = 0; jg < 4; ++jg) {
          acc[mt][jg] = __builtin_amdgcn_mfma_f32_16x16x32_bf16(ah, bh[jg], acc[mt][jg], 0, 0, 0);
          acc[mt][jg] = __builtin_amdgcn_mfma_f32_16x16x32_bf16(ah, bl[jg], acc[mt][jg], 0, 0, 0);
          acc[mt][jg] = __builtin_amdgcn_mfma_f32_16x16x32_bf16(al, bh[jg], acc[mt][jg], 0, 0, 0);
        }
      }
    }
  }

  #pragma unroll
  for (int mt = 0; mt < 4; ++mt)
    #pragma unroll
    for (int jg = 0; jg < 4; ++jg)
      #pragma unroll
      for (int r = 0; r < 4; ++r)
        Obuf[w][mt * 16 + g * 4 + r][jg * 16 + m] = acc[mt][jg][r];
  __syncthreads();

  const int co_l = tid >> 2;
  const int pxq = (tid & 3) * 16;
  float* op = out + ((size_t)b * CO2 + cot * 64 + co_l) * NPIX + p0 + pxq;
  #pragma unroll
  for (int i = 0; i < 4; ++i) {
    float4 s;
    s.x = Obuf[0][co_l][pxq + i * 4 + 0] + Obuf[1][co_l][pxq + i * 4 + 0]
        + Obuf[2][co_l][pxq + i * 4 + 0] + Obuf[3][co_l][pxq + i * 4 + 0];
    s.y = Obuf[0][co_l][pxq + i * 4 + 1] + Obuf[1][co_l][pxq + i * 4 + 1]
        + Obuf[2][co_l][pxq + i * 4 + 1] + Obuf[3][co_l][pxq + i * 4 + 1];
    s.z = Obuf[0][co_l][pxq + i * 4 + 2] + Obuf[1][co_l][pxq + i * 4 + 2]
        + Obuf[2][co_l][pxq + i * 4 + 2] + Obuf[3][co_l][pxq + i * 4 + 2];
    s.w = Obuf[0][co_l][pxq + i * 4 + 3] + Obuf[1][co_l][pxq + i * 4 + 3]
        + Obuf[2][co_l][pxq + i * 4 + 3] + Obuf[3][co_l][pxq + i * 4 + 3];
    *reinterpret_cast<float4*>(&op[i * 4]) = s;
  }
}

// ---------------------------------------------------------------------------
__global__ __launch_bounds__(256) void gn_stats_kernel(
    const float* __restrict__ conv, float* __restrict__ meanb, float* __restrict__ rstdb)
{
  const int g = blockIdx.x;
  const float* base = conv + (size_t)g * (4 * NPIX);
  float s = 0.f, ss = 0.f;
  const float4* b4 = reinterpret_cast<const float4*>(base);
  for (int i = threadIdx.x; i < 4096; i += 256) {
    float4 v = b4[i];
    s += v.x + v.y + v.z + v.w;
    ss += v.x * v.x + v.y * v.y + v.z * v.z + v.w * v.w;
  }
  #pragma unroll
  for (int off = 32; off > 0; off >>= 1) {
    s += __shfl_down(s, off);
    ss += __shfl_down(ss, off);
  }
  __shared__ float rs[4], rss[4];
  const int lane = threadIdx.x & 63, wv = threadIdx.x >> 6;
  if (lane == 0) { rs[wv] = s; rss[wv] = ss; }
  __syncthreads();
  if (threadIdx.x == 0) {
    const float S = rs[0] + rs[1] + rs[2] + rs[3];
    const float SS = rss[0] + rss[1] + rss[2] + rss[3];
    const float inv = 1.f / 16384.f;
    const float m = S * inv;
    const float var = SS * inv - m * m;
    meanb[g] = m;
    rstdb[g] = rsqrtf(var + EPSV);
  }
}

// Fused GN-apply + ReLU + fragment packs (pam: K/V bf16; cam: hi/lo gram frags).
__global__ __launch_bounds__(256) void gn_pack_kernel(
    float* __restrict__ conv, const float* __restrict__ meanb, const float* __restrict__ rstdb,
    const float* __restrict__ sc_pam, const float* __restrict__ bi_pam,
    const float* __restrict__ sc_cam, const float* __restrict__ bi_cam,
    unsigned short* __restrict__ Kf2, unsigned short* __restrict__ Vf2,
    unsigned short* __restrict__ Cfhi, unsigned short* __restrict__ Cflo)
{
  const int px0 = blockIdx.x * 64;
  const int c0  = blockIdx.y * 32;
  const int b   = blockIdx.z;
  __shared__ float Tl[32][72];
  const int t = threadIdx.x;
  {
    const int cl = t >> 3, pg = t & 7;
    const int c = c0 + cl;
    const int gi = (b * 256 + c) >> 2;
    const int head = c >> 7, cc = c & 127;
    const float mean = meanb[gi], rstd = rstdb[gi];
    const float sc = head ? sc_cam[cc] : sc_pam[cc];
    const float bi = head ? bi_cam[cc] : bi_pam[cc];
    float* src = conv + ((size_t)b * CO2 + c) * NPIX + px0 + pg * 8;
    float4 v0 = *reinterpret_cast<const float4*>(src);
    float4 v1 = *reinterpret_cast<const float4*>(src + 4);
    v0.x = fmaxf((v0.x - mean) * rstd * sc + bi, 0.f);
    v0.y = fmaxf((v0.y - mean) * rstd * sc + bi, 0.f);
    v0.z = fmaxf((v0.z - mean) * rstd * sc + bi, 0.f);
    v0.w = fmaxf((v0.w - mean) * rstd * sc + bi, 0.f);
    v1.x = fmaxf((v1.x - mean) * rstd * sc + bi, 0.f);
    v1.y = fmaxf((v1.y - mean) * rstd * sc + bi, 0.f);
    v1.z = fmaxf((v1.z - mean) * rstd * sc + bi, 0.f);
    v1.w = fmaxf((v1.w - mean) * rstd * sc + bi, 0.f);
    *reinterpret_cast<float4*>(src) = v0;
    *reinterpret_cast<float4*>(src + 4) = v1;
    Tl[cl][pg * 8 + 0] = v0.x; Tl[cl][pg * 8 + 1] = v0.y;
    Tl[cl][pg * 8 + 2] = v0.z; Tl[cl][pg * 8 + 3] = v0.w;
    Tl[cl][pg * 8 + 4] = v1.x; Tl[cl][pg * 8 + 5] = v1.y;
    Tl[cl][pg * 8 + 6] = v1.z; Tl[cl][pg * 8 + 7] = v1.w;
  }
  __syncthreads();
  if (c0 < CD) {
    unsigned short* Kb = Kf2 + (size_t)b * 524288;
    unsigned short* Vb = Vf2 + (size_t)b * 524288;
    {
      const int jblk_l = t >> 6, rem = t & 63;
      const int gk = rem >> 4, mk = rem & 15;
      const int jblk = (px0 >> 4) + jblk_l;
      const int kk = c0 >> 5;
      unsigned short h[8];
      #pragma unroll
      for (int e = 0; e < 8; ++e) h[e] = f2bf(Tl[gk * 8 + e][jblk_l * 16 + mk]);
      uint4 packed;
      packed.x = (unsigned)h[0] | ((unsigned)h[1] << 16);
      packed.y = (unsigned)h[2] | ((unsigned)h[3] << 16);
      packed.z = (unsigned)h[4] | ((unsigned)h[5] << 16);
      packed.w = (unsigned)h[6] | ((unsigned)h[7] << 16);
      *reinterpret_cast<uint4*>(&Kb[(size_t)(jblk * 16 + kk * 4 + gk) * 128 + mk * 8]) = packed;
    }
    {
      const int ct_l = t >> 7, kt = (t >> 6) & 1, gv = (t >> 4) & 3, mv = t & 15;
      const int ct = (c0 >> 4) + ct_l;
      const int jc = px0 >> 6;
      unsigned short h[8];
      #pragma unroll
      for (int e = 0; e < 8; ++e) h[e] = f2bf(Tl[ct_l * 16 + mv][kt * 32 + gv * 8 + e]);
      uint4 packed;
      packed.x = (unsigned)h[0] | ((unsigned)h[1] << 16);
      packed.y = (unsigned)h[2] | ((unsigned)h[3] << 16);
      packed.z = (unsigned)h[4] | ((unsigned)h[5] << 16);
      packed.w = (unsigned)h[6] | ((unsigned)h[7] << 16);
      *reinterpret_cast<uint4*>(
          &Vb[(size_t)(((ct * 64 + jc) * 2 + kt) * 4 + gv) * 128 + mv * 8]) = packed;
    }
  } else {
    const int ct_l = t >> 7, kk_l = (t >> 6) & 1, gc = (t >> 4) & 3, mc = t & 15;
    const int ctg = ((c0 - CD) >> 4) + ct_l;
    const int kkg = (px0 >> 5) + kk_l;
    unsigned short hh[8], ll[8];
    #pragma unroll
    for (int e = 0; e < 8; ++e)
      f2bf_pair(Tl[ct_l * 16 + mc][kk_l * 32 + gc * 8 + e], hh[e], ll[e]);
    uint4 ph, pl;
    ph.x = (unsigned)hh[0] | ((unsigned)hh[1] << 16);
    ph.y = (unsigned)hh[2] | ((unsigned)hh[3] << 16);
    ph.z = (unsigned)hh[4] | ((unsigned)hh[5] << 16);
    ph.w = (unsigned)hh[6] | ((unsigned)hh[7] << 16);
    pl.x = (unsigned)ll[0] | ((unsigned)ll[1] << 16);
    pl.y = (unsigned)ll[2] | ((unsigned)ll[3] << 16);
    pl.z = (unsigned)ll[4] | ((unsigned)ll[5] << 16);
    pl.w = (unsigned)ll[6] | ((unsigned)ll[7] << 16);
    const size_t o = (((size_t)(b * 128 + kkg) * 8 + ctg) * 4 + gc) * 128 + mc * 8;
    *reinterpret_cast<uint4*>(&Cfhi[o]) = ph;
    *reinterpret_cast<uint4*>(&Cflo[o]) = pl;
  }
}

// ---------------------------------------------------------------------------
// CAM gram via split-bf16 MFMA, K split across blocks (round-21 proven).
__global__ __launch_bounds__(512) void cam_gram_mfma_kernel(
    const unsigned short* __restrict__ Cfhi, const unsigned short* __restrict__ Cflo,
    float* __restrict__ gpart8)
{
  const int dt = blockIdx.x;
  const int b = blockIdx.y;
  const int kg = blockIdx.z;
  const int tid = threadIdx.x;
  const int w = tid >> 6;
  const int lane = tid & 63;
  const int m = lane & 15, g = lane >> 4;

  __shared__ float Gbuf[4][128][17];

  f32x4 acc[8];
  #pragma unroll
  for (int ct = 0; ct < 8; ++ct)
    #pragma unroll
    for (int r = 0; r < 4; ++r) acc[ct][r] = 0.f;

  const int kk = kg * 8 + w;
  const size_t base = (size_t)(b * 128 + kk) * 8;
  const bf16x8 dh = *reinterpret_cast<const bf16x8*>(&Cfhi[((base + dt) * 4 + g) * 128 + m * 8]);
  const bf16x8 dl = *reinterpret_cast<const bf16x8*>(&Cflo[((base + dt) * 4 + g) * 128 + m * 8]);
  #pragma unroll
  for (int ct = 0; ct < 8; ++ct) {
    const bf16x8 ah = *reinterpret_cast<const bf16x8*>(&Cfhi[((base + ct) * 4 + g) * 128 + m * 8]);
    const bf16x8 al = *reinterpret_cast<const bf16x8*>(&Cflo[((base + ct) * 4 + g) * 128 + m * 8]);
    acc[ct] = __builtin_amdgcn_mfma_f32_16x16x32_bf16(ah, dh, acc[ct], 0, 0, 0);
    acc[ct] = __builtin_amdgcn_mfma_f32_16x16x32_bf16(ah, dl, acc[ct], 0, 0, 0);
    acc[ct] = __builtin_amdgcn_mfma_f32_16x16x32_bf16(al, dh, acc[ct], 0, 0, 0);
  }

  if (w < 4) {
    #pragma unroll
    for (int ct = 0; ct < 8; ++ct)
      #pragma unroll
      for (int r = 0; r < 4; ++r)
        Gbuf[w][ct * 16 + g * 4 + r][m] = acc[ct][r];
  }
  __syncthreads();
  if (w >= 4) {
    #pragma unroll
    for (int ct = 0; ct < 8; ++ct)
      #pragma unroll
      for (int r = 0; r < 4; ++r)
        Gbuf[w - 4][ct * 16 + g * 4 + r][m] += acc[ct][r];
  }
  __syncthreads();
  const int c = tid >> 2;
  const int d0 = (tid & 3) * 4;
  float* gp = gpart8 + (((size_t)(kg * BB + b) * 128 + c)) * 128 + dt * 16;
  #pragma unroll
  for (int j = 0; j < 4; ++j) {
    const int d = d0 + j;
    gp[d] = Gbuf[0][c][d] + Gbuf[1][c][d] + Gbuf[2][c][d] + Gbuf[3][c][d];
  }
}

// Reduce 16 kg partials + row softmax -> camw[b][c][d].
__global__ __launch_bounds__(128) void cam_softmax_kernel(
    const float* __restrict__ gpart8, float* __restrict__ camw)
{
  const int bc = blockIdx.x;
  const int b = bc >> 7, c = bc & 127;
  const int d = threadIdx.x;
  float g = 0.f;
  #pragma unroll
  for (int s = 0; s < 16; ++s)
    g += gpart8[(((size_t)(s * BB + b) * 128 + c)) * 128 + d];
  float m = g;
  #pragma unroll
  for (int off = 32; off > 0; off >>= 1) m = fmaxf(m, __shfl_xor(m, off));
  __shared__ float sm[2], ssum[2];
  const int lane = d & 63, wv = d >> 6;
  if (lane == 0) sm[wv] = m;
  __syncthreads();
  m = fmaxf(sm[0], sm[1]);
  const float e = __expf(g - m);
  float s = e;
  #pragma unroll
  for (int off = 32; off > 0; off >>= 1) s += __shfl_xor(s, off);
  if (lane == 0) ssum[wv] = s;
  __syncthreads();
  camw[(size_t)bc * CD + d] = e / (ssum[0] + ssum[1]);
}

// sum_cam = cam + camw @ Am. Block: (4 ntiles, 32 c-rows, b); thread: 4c x 4n.
__global__ __launch_bounds__(256) void cam_apply_kernel(
    const float* __restrict__ conv, const float* __restrict__ camw, float* __restrict__ scam)
{
  const int b = blockIdx.z;
  const int c0 = blockIdx.y * 4;
  const int n = blockIdx.x * 1024 + threadIdx.x;
  const float* Am = conv + ((size_t)b * CO2 + CD) * NPIX;
  const float* Wr = camw + ((size_t)b * CD + c0) * CD;
  float acc[4][4];
  #pragma unroll
  for (int i = 0; i < 4; ++i)
    #pragma unroll
    for (int k = 0; k < 4; ++k) acc[i][k] = 0.f;
  for (int d = 0; d < CD; ++d) {
    const float w0 = Wr[d], w1 = Wr[CD + d], w2 = Wr[2 * CD + d], w3 = Wr[3 * CD + d];
    #pragma unroll
    for (int k = 0; k < 4; ++k) {
      const float a = Am[(size_t)d * NPIX + n + k * 256];
      acc[0][k] += w0 * a; acc[1][k] += w1 * a;
      acc[2][k] += w2 * a; acc[3][k] += w3 * a;
    }
  }
  #pragma unroll
  for (int i = 0; i < 4; ++i)
    #pragma unroll
    for (int k = 0; k < 4; ++k)
      scam[((size_t)b * CD + c0 + i) * NPIX + n + k * 256] =
          Am[(size_t)(c0 + i) * NPIX + n + k * 256] + acc[i][k];
}

// ---------------------------------------------------------------------------
// PAM flash attention via bf16 MFMA, fragment-packed K/V (round-22 proven).
__global__ __launch_bounds__(512) void pam_mfma_kernel(
    const unsigned short* __restrict__ Kf2, const unsigned short* __restrict__ Vf2,
    unsigned short* __restrict__ Opart, float* __restrict__ mpart,
    float* __restrict__ lpart)
{
  const int tile = blockIdx.x;
  const int b = blockIdx.y;
  const int kg = blockIdx.z;
  const int q0 = tile * 32;
  const int tid = threadIdx.x;
  const int w = tid >> 6;
  const int lane = tid & 63;
  const int m = lane & 15, g = lane >> 4;

  __shared__ __align__(16) unsigned short Sl[8][32 * 72];
  __shared__ unsigned short Obuf[4][32][130];
  __shared__ float mlm[8][32], mll[8][32], mst[32], ltt[32];

  const unsigned short* Kb = Kf2 + (size_t)b * 524288;
  const unsigned short* Vb = Vf2 + (size_t)b * 524288;

  bf16x8 qf[2][4];
  #pragma unroll
  for (int s = 0; s < 2; ++s)
    #pragma unroll
    for (int kk = 0; kk < 4; ++kk)
      qf[s][kk] = *reinterpret_cast<const bf16x8*>(
          &Kb[(size_t)(((q0 >> 4) + s) * 16 + kk * 4 + g) * 128 + m * 8]);

  f32x4 oacc[2][8];
  #pragma unroll
  for (int s = 0; s < 2; ++s)
    #pragma unroll
    for (int ct = 0; ct < 8; ++ct)
      #pragma unroll
      for (int r = 0; r < 4; ++r) oacc[s][ct][r] = 0.f;

  float mrow[2][4], lrow[2][4];
  #pragma unroll
  for (int s = 0; s < 2; ++s)
    #pragma unroll
    for (int r = 0; r < 4; ++r) { mrow[s][r] = -1e30f; lrow[s][r] = 0.f; }

  for (int t = kg * 32 + w * 4; t < kg * 32 + w * 4 + 4; ++t) {
    f32x4 sacc[2][4];
    #pragma unroll
    for (int s = 0; s < 2; ++s)
      #pragma unroll
      for (int jt = 0; jt < 4; ++jt)
        #pragma unroll
        for (int r = 0; r < 4; ++r) sacc[s][jt][r] = 0.f;
    #pragma unroll
    for (int jt = 0; jt < 4; ++jt) {
      #pragma unroll
      for (int kk = 0; kk < 4; ++kk) {
        const bf16x8 kf = *reinterpret_cast<const bf16x8*>(
            &Kb[(size_t)((t * 4 + jt) * 16 + kk * 4 + g) * 128 + m * 8]);
        sacc[0][jt] = __builtin_amdgcn_mfma_f32_16x16x32_bf16(qf[0][kk], kf, sacc[0][jt], 0, 0, 0);
        sacc[1][jt] = __builtin_amdgcn_mfma_f32_16x16x32_bf16(qf[1][kk], kf, sacc[1][jt], 0, 0, 0);
      }
    }
    float facq[2];
    #pragma unroll
    for (int s = 0; s < 2; ++s) {
      float fac[4];
      #pragma unroll
      for (int r = 0; r < 4; ++r) {
        float v = fmaxf(fmaxf(sacc[s][0][r], sacc[s][1][r]), fmaxf(sacc[s][2][r], sacc[s][3][r]));
        v = fmaxf(v, __shfl_xor(v, 1));
        v = fmaxf(v, __shfl_xor(v, 2));
        v = fmaxf(v, __shfl_xor(v, 4));
        v = fmaxf(v, __shfl_xor(v, 8));
        const float mn = fmaxf(mrow[s][r], v);
        fac[r] = __expf(fmaxf(mrow[s][r] - mn, -80.f));
        mrow[s][r] = mn;
      }
      #pragma unroll
      for (int r = 0; r < 4; ++r) {
        float ls = 0.f;
        #pragma unroll
        for (int jt = 0; jt < 4; ++jt) {
          const float e = __expf(sacc[s][jt][r] - mrow[s][r]);
          ls += e;
          Sl[w][(s * 16 + g * 4 + r) * 72 + jt * 16 + m] = f2bf(e);
        }
        ls += __shfl_xor(ls, 1);
        ls += __shfl_xor(ls, 2);
        ls += __shfl_xor(ls, 4);
        ls += __shfl_xor(ls, 8);
        lrow[s][r] = lrow[s][r] * fac[r] + ls;
      }
      const int sel = m & 3;
      const float fsel = (sel == 0) ? fac[0] : (sel == 1) ? fac[1] : (sel == 2) ? fac[2] : fac[3];
      facq[s] = __shfl(fsel, ((m >> 2) << 4) | sel);
    }
    #pragma unroll
    for (int s = 0; s < 2; ++s)
      #pragma unroll
      for (int ct = 0; ct < 8; ++ct)
        #pragma unroll
        for (int r = 0; r < 4; ++r) oacc[s][ct][r] *= facq[s];
    bf16x8 pf[2][2];
    #pragma unroll
    for (int s = 0; s < 2; ++s)
      #pragma unroll
      for (int kt = 0; kt < 2; ++kt)
        pf[s][kt] = *reinterpret_cast<const bf16x8*>(&Sl[w][(s * 16 + m) * 72 + kt * 32 + g * 8]);
    #pragma unroll
    for (int ct = 0; ct < 8; ++ct) {
      #pragma unroll
      for (int kt = 0; kt < 2; ++kt) {
        const bf16x8 vf = *reinterpret_cast<const bf16x8*>(
            &Vb[(size_t)(((ct * 64 + t) * 2 + kt) * 4 + g) * 128 + m * 8]);
        oacc[0][ct] = __builtin_amdgcn_mfma_f32_16x16x32_bf16(vf, pf[0][kt], oacc[0][ct], 0, 0, 0);
        oacc[1][ct] = __builtin_amdgcn_mfma_f32_16x16x32_bf16(vf, pf[1][kt], oacc[1][ct], 0, 0, 0);
      }
    }
  }

  float mq[2], lq[2];
  #pragma unroll
  for (int s = 0; s < 2; ++s) {
    const int sel = m & 3;
    const float msel_ = (sel == 0) ? mrow[s][0] : (sel == 1) ? mrow[s][1]
                       : (sel == 2) ? mrow[s][2] : mrow[s][3];
    mq[s] = __shfl(msel_, ((m >> 2) << 4) | sel);
    const float lsel_ = (sel == 0) ? lrow[s][0] : (sel == 1) ? lrow[s][1]
                       : (sel == 2) ? lrow[s][2] : lrow[s][3];
    lq[s] = __shfl(lsel_, ((m >> 2) << 4) | sel);
  }
  if (g == 0) {
    #pragma unroll
    for (int s = 0; s < 2; ++s) { mlm[w][s * 16 + m] = mq[s]; mll[w][s * 16 + m] = lq[s]; }
  }
  __syncthreads();
  float rsw[2];
  #pragma unroll
  for (int s = 0; s < 2; ++s) {
    const int row = s * 16 + m;
    float ms = mlm[0][row];
    #pragma unroll
    for (int sw = 1; sw < 8; ++sw) ms = fmaxf(ms, mlm[sw][row]);
    rsw[s] = __expf(fmaxf(mq[s] - ms, -80.f));
  }
  if (w < 4) {
    #pragma unroll
    for (int s = 0; s < 2; ++s)
      #pragma unroll
      for (int ct = 0; ct < 8; ++ct)
        #pragma unroll
        for (int r = 0; r < 4; ++r)
          Obuf[w][s * 16 + m][ct * 16 + g * 4 + r] = f2bf(oacc[s][ct][r] * rsw[s]);
  }
  if (w == 0 && g == 0) {
    #pragma unroll
    for (int s = 0; s < 2; ++s) {
      const int row = s * 16 + m;
      float ms = mlm[0][row];
      #pragma unroll
      for (int sw = 1; sw < 8; ++sw) ms = fmaxf(ms, mlm[sw][row]);
      float lt = 0.f;
      #pragma unroll
      for (int sw = 0; sw < 8; ++sw)
        lt += mll[sw][row] * __expf(fmaxf(mlm[sw][row] - ms, -80.f));
      mst[row] = ms;
      ltt[row] = lt;
    }
  }
  __syncthreads();
  if (w >= 4) {
    #pragma unroll
    for (int s = 0; s < 2; ++s)
      #pragma unroll
      for (int ct = 0; ct < 8; ++ct)
        #pragma unroll
        for (int r = 0; r < 4; ++r) {
          unsigned short* pp = &Obuf[w - 4][s * 16 + m][ct * 16 + g * 4 + r];
          *pp = f2bf(bf2f(*pp) + oacc[s][ct][r] * rsw[s]);
        }
  }
  __syncthreads();
  const size_t pbase = ((size_t)(kg * BB + b) * 128 + tile) * 32;
  unsigned short* Op = Opart + pbase * 128;
  const int c = tid >> 2;
  const int qh = (tid & 3) * 8;
  #pragma unroll
  for (int qq = 0; qq < 8; ++qq) {
    const int row = qh + qq;
    float o = 0.f;
    #pragma unroll
    for (int sw = 0; sw < 4; ++sw) o += bf2f(Obuf[sw][row][c]);
    Op[(size_t)row * 128 + c] = f2bf(o);
  }
  if (tid < 32) {
    mpart[pbase + tid] = mst[tid];
    lpart[pbase + tid] = ltt[tid];
  }
}

// Combine the two kg partials exactly; add conv residual.
__global__ __launch_bounds__(256) void pam_merge_kernel(
    const float* __restrict__ conv, const unsigned short* __restrict__ Opart,
    const float* __restrict__ mpart, const float* __restrict__ lpart,
    float* __restrict__ spam)
{
  const int tile = blockIdx.x;
  const int b = blockIdx.y;
  const int tid = threadIdx.x;
  const int c = tid & 127;
  const int rg = tid >> 7;
  const size_t i0 = ((size_t)(0 * BB + b) * 128 + tile) * 32;
  const size_t i1 = ((size_t)(1 * BB + b) * 128 + tile) * 32;
  #pragma unroll
  for (int rr = 0; rr < 16; ++rr) {
    const int row = rg * 16 + rr;
    const float m0 = mpart[i0 + row], m1 = mpart[i1 + row];
    const float ms = fmaxf(m0, m1);
    const float w0 = __expf(fmaxf(m0 - ms, -80.f));
    const float w1 = __expf(fmaxf(m1 - ms, -80.f));
    const float l = lpart[i0 + row] * w0 + lpart[i1 + row] * w1;
    const float o = bf2f(Opart[(i0 + row) * 128 + c]) * w0
                  + bf2f(Opart[(i1 + row) * 128 + c]) * w1;
    const int q = tile * 32 + row;
    spam[((size_t)b * CD + c) * NPIX + q] =
        conv[((size_t)b * CO2 + c) * NPIX + q] + o / l;
  }
}

// ---------------------------------------------------------------------------
__global__ __launch_bounds__(256) void pred_part_kernel(
    const float* __restrict__ spam, const float* __restrict__ scam,
    const float* __restrict__ wpred, float* __restrict__ psum)
{
  const int p = blockIdx.x * 256 + threadIdx.x;
  const int slice = blockIdx.y;
  const int b = blockIdx.z;
  float acc[KOUT];
  #pragma unroll
  for (int k = 0; k < KOUT; ++k) acc[k] = 0.f;
  const float* sp = spam + (size_t)b * CD * NPIX + p;
  const float* sc = scam + (size_t)b * CD * NPIX + p;
  #pragma unroll
  for (int ci = 0; ci < 16; ++ci) {
    const int c = slice * 16 + ci;
    const float f = sp[(size_t)c * NPIX] + sc[(size_t)c * NPIX];
    #pragma unroll
    for (int k = 0; k < KOUT; ++k)
      acc[k] += f * wpred[k * CD + c];
  }
  #pragma unroll
  for (int k = 0; k < KOUT; ++k)
    psum[(((size_t)slice * BB + b) * KOUT + k) * NPIX + p] = acc[k];
}

__global__ __launch_bounds__(256) void pred_reduce_kernel(
    const float* __restrict__ psum, const float* __restrict__ bpred,
    float* __restrict__ logit)
{
  const int p = blockIdx.x * 256 + threadIdx.x;
  const int b = blockIdx.y;
  #pragma unroll
  for (int k = 0; k < KOUT; ++k) {
    float s = bpred[k];
    #pragma unroll
    for (int sl = 0; sl < 8; ++sl)
      s += psum[(((size_t)sl * BB + b) * KOUT + k) * NPIX + p];
    logit[((size_t)b * KOUT + k) * NPIX + p] = s;
  }
}

__global__ __launch_bounds__(256) void upsample_kernel(
    const float* __restrict__ logit, float* __restrict__ out)
{
  const int idx = blockIdx.x * 256 + threadIdx.x;
  if (idx >= BB * KOUT * 256 * 256) return;
  const int ox = idx & 255;
  const int oy = (idx >> 8) & 255;
  const int plane = idx >> 16;
  const float* src = logit + (size_t)plane * NPIX;
  const float sy = (oy + 0.5f) * 0.25f - 0.5f;
  const float sx = (ox + 0.5f) * 0.25f - 0.5f;
  const float fyf = floorf(sy), fxf = floorf(sx);
  const float wy = sy - fyf, wx = sx - fxf;
  const int y0 = (int)fyf, x0 = (int)fxf;
  const int y0c = y0 < 0 ? 0 : y0;
  const int y1c = (y0 + 1 > 63) ? 63 : y0 + 1;
  const int x0c = x0 < 0 ? 0 : x0;
  const int x1c = (x0 + 1 > 63) ? 63 : x0 + 1;
  const float v00 = src[y0c * 64 + x0c], v01 = src[y0c * 64 + x1c];
  const float v10 = src[y1c * 64 + x0c], v11 = src[y1c * 64 + x1c];
  const float top = v00 + (v01 - v00) * wx;
  const float bot = v10 + (v11 - v10) * wx;
  out[idx] = top + (bot - top) * wy;
}

// ---------------------------------------------------------------------------
extern "C" void kernel_launch(void* const* d_in, const int* in_sizes, int n_in,
                              void* d_out, int out_size, void* d_ws, size_t ws_size,
                              hipStream_t stream) {
  (void)in_sizes; (void)n_in; (void)out_size; (void)ws_size;
  const float* x      = (const float*)d_in[0];
  const float* w_pam  = (const float*)d_in[1];
  const float* s_pam  = (const float*)d_in[2];
  const float* b_pam  = (const float*)d_in[3];
  const float* w_cam  = (const float*)d_in[4];
  const float* s_cam  = (const float*)d_in[5];
  const float* b_cam  = (const float*)d_in[6];
  const float* w_pred = (const float*)d_in[7];
  const float* b_pred = (const float*)d_in[8];
  float* out_f = (float*)d_out;
  float* ws0 = (float*)d_ws;

  // workspace layout (floats), total 5,138,688 = 20.55 MB (round-22 proven)
  float* conv  = ws0;
  unsigned short* xThi = (unsigned short*)(ws0 + 2097152);
  unsigned short* xTlo = xThi + (size_t)BB * 32 * SPAD * 8;
  unsigned short* wbhi = (unsigned short*)(ws0 + 4327424);
  unsigned short* wblo = wbhi + (size_t)CO2 * KW9;
  unsigned short* Cfhi = (unsigned short*)(ws0 + 3145728);
  unsigned short* Cflo = (unsigned short*)(ws0 + 3670016);
  unsigned short* Opart = (unsigned short*)(ws0 + 3145728);
  float* psum  = ws0 + 3145728;
  float* mpart = ws0 + 4194304;
  float* lpart = ws0 + 4227072;
  float* gpart8 = ws0 + 4292608;
  float* camw  = ws0 + 4950016;
  float* meanb = ws0 + 4982784;
  float* rstdb = ws0 + 4982912;
  float* logit = ws0 + 4983040;

  unsigned short* Kf2 = xThi;
  unsigned short* Vf2 = Kf2 + 1048576;

  float* spam = out_f;
  float* scam = out_f + 1048576;

  zhalo_kernel<<<dim3(260, 2), 64, 0, stream>>>(xThi, xTlo);
  xpose_kernel<<<dim3(64, 8, 2), 256, 0, stream>>>(x, xThi, xTlo);
  wbconv_kernel<<<256, 256, 0, stream>>>(w_pam, w_cam, wbhi, wblo);
  conv_mfma_kernel<<<dim3(64, 4, 2), 256, 0, stream>>>(xThi, xTlo, wbhi, wblo, conv);
  gn_stats_kernel<<<128, 256, 0, stream>>>(conv, meanb, rstdb);
  gn_pack_kernel<<<dim3(64, 8, 2), 256, 0, stream>>>(conv, meanb, rstdb,
      s_pam, b_pam, s_cam, b_cam, Kf2, Vf2, Cfhi, Cflo);
  cam_gram_mfma_kernel<<<dim3(8, 2, 16), 512, 0, stream>>>(Cfhi, Cflo, gpart8);
  cam_softmax_kernel<<<256, 128, 0, stream>>>(gpart8, camw);
  cam_apply_kernel<<<dim3(4, 32, 2), 256, 0, stream>>>(conv, camw, scam);
  pam_mfma_kernel<<<dim3(128, 2, 2), 512, 0, stream>>>(Kf2, Vf2, Opart, mpart, lpart);
  pam_merge_kernel<<<dim3(128, 2), 256, 0, stream>>>(conv, Opart, mpart, lpart, spam);
  pred_part_kernel<<<dim3(16, 8, 2), 256, 0, stream>>>(spam, scam, w_pred, psum);
  pred_reduce_kernel<<<dim3(16, 2), 256, 0, stream>>>(psum, b_pred, logit);
  upsample_kernel<<<9728, 256, 0, stream>>>(logit, out_f);
}